// Round 6
// baseline (228.084 us; speedup 1.0000x reference)
//
#include <hip/hip_runtime.h>
#include <stdint.h>

// Wavelet low-pass analysis (stride-2) + synthesis (transposed conv) fused
// into two 18-tap polyphase FIR filters applied directly to the input:
//   even p: ya[p] = sum_d We[d] * sig_m[p - 8 + d]
//   odd  p: ya[p] = sum_d Wo[d] * sig_m[p - 9 + d]
// sig_m = symmetric extension of the 524288-long flattened per-batch signal.
//
// v7: dispatch-rate probe. v6 confirmed the champion per-thread structure
// (1 quad/thread, 5 ds_read_b128, 72 FMA, plain store; DMA staging neutral
// vs VGPR staging). Remaining gap to the ~41us BW floor shows every pipe
// idle -> suspect the 32768 one-shot workgroups hit the per-XCD dispatch
// rate (~41 cyc/wg). This version keeps per-thread code IDENTICAL and only
// grows the block: 1024 threads, TILE 4096 -> 8192 blocks (4x fewer
// dispatches), 16 waves/block, 2 blocks/CU (full 32-wave occupancy),
// LDS 16.5 KB.

#define L_SIG 524288            // flattened per-batch length (128*4096) = 2^19
#define TILE  4096
#define NTHR  1024
#define HALO  16                // only +-9 needed; 16 keeps float4 alignment
#define SMEM_N (TILE + 2 * HALO) // 4128 floats = 16512 B

typedef float f4 __attribute__((ext_vector_type(4)));

typedef __attribute__((address_space(3))) uint32_t lds_u32_t;
typedef const __attribute__((address_space(1))) uint32_t glb_u32_t;

// Async global->LDS DMA, 16 B per lane. LDS dest is wave-uniform base +
// lane*16 (m104) -- lane-linear layout matches exactly (verified r2/r4/r5).
__device__ __forceinline__ void stage16(const float* g, float* l) {
    __builtin_amdgcn_global_load_lds((glb_u32_t*)g, (lds_u32_t*)l, 16, 0, 0);
}

constexpr float RL[10] = {
    0.160102397974125f,   0.6038292697974729f,  0.7243085284385744f,
    0.13842814590110342f, -0.24229488706619015f, -0.03224486958502952f,
    0.07757149384006515f, -0.006241490213011705f, -0.012580751999015526f,
    0.003335725285001549f};

struct Coef { float we[18]; float wo[18]; };

constexpr Coef make_coef() {
    Coef c{};
    for (int d = 0; d < 18; ++d) {
        float se = 0.f, so = 0.f;
        for (int j = 0; j < 5; ++j) {
            int i = d - 2 * j;               // REC_LO tap index
            if (i >= 0 && i < 10) {
                se += RL[8 - 2 * j] * RL[i]; // DEC_LO[2j+1] = RL[8-2j]
                so += RL[9 - 2 * j] * RL[i]; // DEC_LO[2j]   = RL[9-2j]
            }
        }
        c.we[d] = se;
        c.wo[d] = so;
    }
    return c;
}

constexpr Coef CF = make_coef();

__global__ __launch_bounds__(NTHR)
void wavelet_fused_kernel(const float* __restrict__ x, float* __restrict__ out) {
    __shared__ float s[SMEM_N];

    const int batch = blockIdx.y;
    const int p0    = blockIdx.x * TILE;
    const float* xb = x   + (size_t)batch * L_SIG;
    float*       ob = out + (size_t)batch * L_SIG;
    const int t = threadIdx.x;

    const bool edge = (blockIdx.x == 0) || (blockIdx.x == gridDim.x - 1);

    if (edge) {
        // Scalar mirror staging (2 blocks/batch = 128 of 8192 blocks).
        // global_load_lds can't express the element-reversed mirror.
        for (int i = t; i < SMEM_N; i += NTHR) {
            int k  = p0 - HALO + i;
            int km = (k < 0) ? (-1 - k) : ((k >= L_SIG) ? (2 * L_SIG - 1 - k) : k);
            s[i] = xb[km];
        }
    } else {
        // Interior: 4128 floats = 1032 float4 via async DMA, 16B-aligned
        // (p0 - 16 is float4-aligned since p0 % 4096 == 0).
        const float* src = xb + p0 - HALO;
        stage16(src + 4 * t, s + 4 * t);
        if (t < 8)
            stage16(src + 4096 + 4 * t, s + 4096 + 4 * t);
    }
    __syncthreads();   // barrier drain waits vmcnt(0): DMA complete

    // One output quad per thread: outputs p0+q .. p0+q+3 (even,odd,even,odd).
    const int q = 4 * t;

    float v[20];
    const f4* sp = (const f4*)(s + q + 8);  // = x[p0 + q - 8 ...]
#pragma unroll
    for (int r = 0; r < 5; ++r) {
        f4 f = sp[r];
        v[4 * r + 0] = f[0];
        v[4 * r + 1] = f[1];
        v[4 * r + 2] = f[2];
        v[4 * r + 3] = f[3];
    }

    float o0 = 0.f, o1 = 0.f, o2 = 0.f, o3 = 0.f;
#pragma unroll
    for (int d = 0; d < 18; ++d) {
        o0 += CF.we[d] * v[d];       // even output at q   : x[q-8+d]
        o1 += CF.wo[d] * v[d];       // odd  output at q+1 : x[(q+1)-9+d]
        o2 += CF.we[d] * v[d + 2];   // even output at q+2
        o3 += CF.wo[d] * v[d + 2];   // odd  output at q+3
    }

    // Plain store: acks at L2, drains to HBM lazily (no barrier follows).
    *((f4*)(ob + p0 + q)) = {o0, o1, o2, o3};
}

extern "C" void kernel_launch(void* const* d_in, const int* in_sizes, int n_in,
                              void* d_out, int out_size, void* d_ws, size_t ws_size,
                              hipStream_t stream) {
    const float* x = (const float*)d_in[0];
    float* out     = (float*)d_out;

    const int B = in_sizes[0] / L_SIG;            // 64
    dim3 grid(L_SIG / TILE, B);                   // (128, 64) = 8192 blocks
    wavelet_fused_kernel<<<grid, NTHR, 0, stream>>>(x, out);
}